// Round 8
// baseline (239.371 us; speedup 1.0000x reference)
//
#include <hip/hip_runtime.h>
#include <math.h>

#define NB 4
#define SEQ 4096
#define NH 32
#define HD 128
#define DIM 4096
#define INTER 11008
#define HC 32
#define HEAVY 256
#define EPS 1e-5f

typedef float f4 __attribute__((ext_vector_type(4)));

__device__ __forceinline__ float dotv(f4 a, f4 b) {
  f4 p = a * b;
  return p.x + p.y + p.z + p.w;
}
__device__ __forceinline__ f4 ld4(const float* p) { return *(const f4*)p; }
__device__ __forceinline__ f4 ldnt(const float* p) {
  return __builtin_nontemporal_load((const f4*)p);
}

__device__ __forceinline__ float wave_sum(float v) {
  #pragma unroll
  for (int off = 32; off; off >>= 1) v += __shfl_down(v, off, 64);
  return v;
}

// ---------- QKV GEMV with fused RMSNorm, rs deferred past the dot ----------
// rmsnorm(x)@w = rs * ((x*nw)@w): no barrier between x load and weight stream.
template<int R>
__global__ __launch_bounds__(256) void qkv_norm_k(const float* __restrict__ w,
                                                  const float* __restrict__ x,
                                                  const float* __restrict__ nw,
                                                  float* __restrict__ out) {
  const int t = threadIdx.x;
  const int r0 = blockIdx.x * R;
  const int lane = t & 63, wi = t >> 6;
  __shared__ float redn[4][NB];
  __shared__ float red[4][R*NB];
  f4 xr[NB][4];
  #pragma unroll
  for (int b = 0; b < NB; ++b)
    #pragma unroll
    for (int j = 0; j < 4; ++j)
      xr[b][j] = ld4(x + b*DIM + (j*256 + t)*4);
  // sumsq -> LDS (read only after the single epilogue barrier)
  #pragma unroll
  for (int b = 0; b < NB; ++b) {
    float ss = 0.f;
    #pragma unroll
    for (int j = 0; j < 4; ++j) ss += dotv(xr[b][j], xr[b][j]);
    ss = wave_sum(ss);
    if (lane == 0) redn[wi][b] = ss;
  }
  // x *= nw only (rs applied at the end)
  #pragma unroll
  for (int j = 0; j < 4; ++j) {
    f4 aw = ld4(nw + (j*256 + t)*4);
    #pragma unroll
    for (int b = 0; b < NB; ++b) xr[b][j] *= aw;
  }
  float acc[R][NB];
  #pragma unroll
  for (int r = 0; r < R; ++r)
    #pragma unroll
    for (int b = 0; b < NB; ++b) acc[r][b] = 0.f;
  #pragma unroll
  for (int r = 0; r < R; ++r) {
    const float* wr = w + (size_t)(r0 + r) * DIM;
    #pragma unroll
    for (int j = 0; j < 4; ++j) {
      f4 wv = ld4(wr + (j*256 + t)*4);
      #pragma unroll
      for (int b = 0; b < NB; ++b) acc[r][b] += dotv(wv, xr[b][j]);
    }
  }
  #pragma unroll
  for (int r = 0; r < R; ++r)
    #pragma unroll
    for (int b = 0; b < NB; ++b) {
      float v = wave_sum(acc[r][b]);
      if (lane == 0) red[wi][r*NB + b] = v;
    }
  __syncthreads();   // single barrier: covers redn AND red
  if (t < R*NB) {
    int r = t >> 2, b = t & 3;
    float rs = rsqrtf((redn[0][b]+redn[1][b]+redn[2][b]+redn[3][b]) * (1.f/DIM) + EPS);
    float s = red[0][t] + red[1][t] + red[2][t] + red[3][t];
    out[(size_t)b*(3*DIM) + r0 + r] = rs * s;
  }
}

// ---------- Wo GEMV + residual, R rows/block (NT weights) ----------
template<int R>
__global__ __launch_bounds__(256) void wo_k(const float* __restrict__ w,
                                            const float* __restrict__ x,
                                            const float* __restrict__ resid,
                                            float* __restrict__ out) {
  const int t = threadIdx.x;
  const int r0 = blockIdx.x * R;
  f4 xr[NB][4];
  #pragma unroll
  for (int b = 0; b < NB; ++b)
    #pragma unroll
    for (int j = 0; j < 4; ++j)
      xr[b][j] = ld4(x + b*DIM + (j*256 + t)*4);
  float acc[R][NB];
  #pragma unroll
  for (int r = 0; r < R; ++r)
    #pragma unroll
    for (int b = 0; b < NB; ++b) acc[r][b] = 0.f;
  #pragma unroll
  for (int r = 0; r < R; ++r) {
    const float* wr = w + (size_t)(r0 + r) * DIM;
    #pragma unroll
    for (int j = 0; j < 4; ++j) {
      f4 wv = ldnt(wr + (j*256 + t)*4);
      #pragma unroll
      for (int b = 0; b < NB; ++b) acc[r][b] += dotv(wv, xr[b][j]);
    }
  }
  __shared__ float red[4][R*NB];
  const int lane = t & 63, wi = t >> 6;
  #pragma unroll
  for (int r = 0; r < R; ++r)
    #pragma unroll
    for (int b = 0; b < NB; ++b) {
      float v = wave_sum(acc[r][b]);
      if (lane == 0) red[wi][r*NB + b] = v;
    }
  __syncthreads();
  if (t < R*NB) {
    int r = t >> 2, b = t & 3;
    float s = red[0][t] + red[1][t] + red[2][t] + red[3][t];
    out[(size_t)b*DIM + r0 + r] = resid[(size_t)b*DIM + r0 + r] + s;
  }
}

// ---------- W1/W3 GEMV + SwiGLU with fused RMSNorm, rs deferred (NT weights) ----------
template<int R>
__global__ __launch_bounds__(256) void ffn13_norm_k(const float* __restrict__ w1,
                                                    const float* __restrict__ w3,
                                                    const float* __restrict__ h,
                                                    const float* __restrict__ nw,
                                                    float* __restrict__ g) {
  const int t = threadIdx.x;
  const int r0 = blockIdx.x * R;
  const int lane = t & 63, wi = t >> 6;
  __shared__ float redn[4][NB];
  __shared__ float red[4][2*R*NB];
  f4 xr[NB][4];
  #pragma unroll
  for (int b = 0; b < NB; ++b)
    #pragma unroll
    for (int j = 0; j < 4; ++j)
      xr[b][j] = ld4(h + b*DIM + (j*256 + t)*4);
  #pragma unroll
  for (int b = 0; b < NB; ++b) {
    float ss = 0.f;
    #pragma unroll
    for (int j = 0; j < 4; ++j) ss += dotv(xr[b][j], xr[b][j]);
    ss = wave_sum(ss);
    if (lane == 0) redn[wi][b] = ss;
  }
  #pragma unroll
  for (int j = 0; j < 4; ++j) {
    f4 aw = ld4(nw + (j*256 + t)*4);
    #pragma unroll
    for (int b = 0; b < NB; ++b) xr[b][j] *= aw;
  }
  float a1[R][NB], a3[R][NB];
  #pragma unroll
  for (int r = 0; r < R; ++r)
    #pragma unroll
    for (int b = 0; b < NB; ++b) { a1[r][b] = 0.f; a3[r][b] = 0.f; }
  #pragma unroll
  for (int r = 0; r < R; ++r) {
    const float* wr1 = w1 + (size_t)(r0 + r) * DIM;
    const float* wr3 = w3 + (size_t)(r0 + r) * DIM;
    #pragma unroll
    for (int j = 0; j < 4; ++j) {
      f4 v1 = ldnt(wr1 + (j*256 + t)*4);
      f4 v3 = ldnt(wr3 + (j*256 + t)*4);
      #pragma unroll
      for (int b = 0; b < NB; ++b) {
        a1[r][b] += dotv(v1, xr[b][j]);
        a3[r][b] += dotv(v3, xr[b][j]);
      }
    }
  }
  #pragma unroll
  for (int r = 0; r < R; ++r)
    #pragma unroll
    for (int b = 0; b < NB; ++b) {
      float v = wave_sum(a1[r][b]);
      if (lane == 0) red[wi][r*NB + b] = v;
      v = wave_sum(a3[r][b]);
      if (lane == 0) red[wi][R*NB + r*NB + b] = v;
    }
  __syncthreads();   // single barrier
  if (t < R*NB) {
    int r = t >> 2, b = t & 3;
    float rs = rsqrtf((redn[0][b]+redn[1][b]+redn[2][b]+redn[3][b]) * (1.f/DIM) + EPS);
    float d1 = rs * (red[0][t] + red[1][t] + red[2][t] + red[3][t]);
    int t3 = R*NB + t;
    float d3 = rs * (red[0][t3] + red[1][t3] + red[2][t3] + red[3][t3]);
    float s = d1 / (1.f + expf(-d1));
    g[(size_t)b*INTER + r0 + r] = s * d3;
  }
}

// ---------- W2 GEMV (K=11008): barrier-free, x from L2 per f4-column ----------
template<int R>
__global__ __launch_bounds__(256) void w2_k(const float* __restrict__ w2,
                                            const float* __restrict__ g,
                                            const float* __restrict__ h,
                                            float* __restrict__ out) {
  const int t = threadIdx.x;
  const int r0 = blockIdx.x * R;
  float acc[R][NB];
  #pragma unroll
  for (int r = 0; r < R; ++r)
    #pragma unroll
    for (int b = 0; b < NB; ++b) acc[r][b] = 0.f;
  // INTER/4 = 2752 f4-columns; thread t owns columns {t + 256*i}, i = 0..10
  #pragma unroll
  for (int i = 0; i < 11; ++i) {
    const int idx = t + i*256;
    if (idx < INTER/4) {
      f4 xv[NB];
      #pragma unroll
      for (int b = 0; b < NB; ++b) xv[b] = ld4(g + (size_t)b*INTER + idx*4);
      #pragma unroll
      for (int r = 0; r < R; ++r) {
        f4 wv = ldnt(w2 + (size_t)(r0 + r)*INTER + idx*4);
        #pragma unroll
        for (int b = 0; b < NB; ++b) acc[r][b] += dotv(wv, xv[b]);
      }
    }
  }
  __shared__ float red[4][R*NB];
  const int lane = t & 63, wi = t >> 6;
  #pragma unroll
  for (int r = 0; r < R; ++r)
    #pragma unroll
    for (int b = 0; b < NB; ++b) {
      float v = wave_sum(acc[r][b]);
      if (lane == 0) red[wi][r*NB + b] = v;
    }
  __syncthreads();
  if (t < R*NB) {
    int r = t >> 2, b = t & 3;
    float s = red[0][t] + red[1][t] + red[2][t] + red[3][t];
    out[(size_t)b*DIM + r0 + r] = h[(size_t)b*DIM + r0 + r] + s;
  }
}

// ---------- fused RoPE + label scores: 4 s-chunks per (b,h), full GPU ----------
// klab_cache cacheable (L3-residency candidate alongside wqkv)
__global__ __launch_bounds__(256) void scores_rope_k(const float* __restrict__ qkv,
                                                     const float* __restrict__ freqs,
                                                     const int* __restrict__ chan,
                                                     const float* __restrict__ klab_cache,
                                                     const int* __restrict__ pos_p,
                                                     uint32_t* __restrict__ su,
                                                     float* __restrict__ q_rot,
                                                     float* __restrict__ k_rot) {
  int bc = blockIdx.x; int c = bc & 3; int bh = bc >> 2;
  int b = bh >> 5, h = bh & 31;
  int pos = *pos_p; int n = pos + 1;
  int t = threadIdx.x;
  __shared__ float qs[HD], ks[HD], qv[HC], kls[HC];
  const float* qp = qkv + (size_t)b*3*DIM + h*HD;
  const float* kp = qp + DIM;
  if (t < 64) {
    float cc = freqs[2*t], sn = freqs[2*t+1];
    float q0 = qp[2*t], q1 = qp[2*t+1];
    float k0 = kp[2*t], k1 = kp[2*t+1];
    qs[2*t] = q0*cc - q1*sn; qs[2*t+1] = q1*cc + q0*sn;
    ks[2*t] = k0*cc - k1*sn; ks[2*t+1] = k1*cc + k0*sn;
  }
  __syncthreads();
  if (t < HC) { int ch = chan[h*HC + t]; qv[t] = qs[ch]; kls[t] = ks[ch]; }
  if (c == 0 && t < HD) {
    q_rot[(size_t)bh*HD + t] = qs[t];
    k_rot[(size_t)bh*HD + t] = ks[t];
  }
  __syncthreads();
  int chunk = (n + 3) >> 2;
  int s0 = c * chunk, s1 = min(n, s0 + chunk);
  for (int s = s0 + t; s < s1; s += 256) {
    float acc = 0.f;
    if (s == pos) {
      #pragma unroll
      for (int j = 0; j < HC; ++j) acc += qv[j] * kls[j];
    } else {
      const float* kl = klab_cache + (((size_t)b*SEQ + s)*NH + h)*HC;
      #pragma unroll
      for (int c4 = 0; c4 < HC/4; ++c4) {
        f4 kv = ld4(kl + c4*4);
        acc += qv[c4*4+0]*kv.x + qv[c4*4+1]*kv.y + qv[c4*4+2]*kv.z + qv[c4*4+3]*kv.w;
      }
    }
    uint32_t u = __float_as_uint(acc);
    u = (u & 0x80000000u) ? ~u : (u | 0x80000000u);   // monotone map, desc order
    su[(size_t)bh*SEQ + s] = u;
  }
}

// ---------- radix top-256 + gather attention, one (b,h) per block ----------
// k/v gathers NT (stream): keep L3 reserved for wqkv + klab_cache
__global__ __launch_bounds__(512) void selattn_k(const uint32_t* __restrict__ su_g,
                                                 const float* __restrict__ q_rot,
                                                 const float* __restrict__ k_rot,
                                                 const float* __restrict__ qkv,
                                                 const float* __restrict__ k_cache,
                                                 const float* __restrict__ v_cache,
                                                 const int* __restrict__ pos_p,
                                                 float* __restrict__ o) {
  const int bh = blockIdx.x, b = bh >> 5, h = bh & 31;
  const int pos = *pos_p, n = pos + 1;
  const int t = threadIdx.x;
  __shared__ uint32_t su[SEQ];          // 16 KB
  __shared__ uint32_t hist[256], sfx[256];
  __shared__ uint32_t sh_prefix, sh_kremain, sh_cnt;
  __shared__ int lidx[HEAVY];
  __shared__ float sc[HEAVY], red8[8];
  __shared__ f4 qb4[HD/4], kb4[HD/4];
  __shared__ f4 ovv[16][32];            // 8 KB
  __shared__ float s_m, s_sum;
  if (t == 0) { sh_prefix = 0; sh_kremain = HEAVY; sh_cnt = 0; }
  if (t < 32) { qb4[t] = ld4(q_rot + (size_t)bh*HD + t*4);
                kb4[t] = ld4(k_rot + (size_t)bh*HD + t*4); }
  for (int s = t; s < n; s += 512) su[s] = su_g[(size_t)bh*SEQ + s];
  __syncthreads();
  // ---- radix-select the 256th-largest (4 passes, parallel suffix scan) ----
  uint32_t prefix = 0;
  for (int pass = 0; pass < 4; ++pass) {
    int shift = 24 - 8*pass;
    if (t < 256) hist[t] = 0;
    __syncthreads();
    for (int s = t; s < n; s += 512) {
      uint32_t u = su[s];
      bool m = (pass == 0) || ((u >> (shift + 8)) == prefix);
      if (m) atomicAdd(&hist[(u >> shift) & 255u], 1u);
    }
    __syncthreads();
    uint32_t need = sh_kremain;
    if (t < 256) sfx[t] = hist[t];
    __syncthreads();
    #pragma unroll
    for (int off = 1; off < 256; off <<= 1) {
      uint32_t v = 0, a = 0;
      if (t < 256) { v = sfx[t]; a = (t + off < 256) ? sfx[t + off] : 0u; }
      __syncthreads();
      if (t < 256) sfx[t] = v + a;
      __syncthreads();
    }
    if (t < 256 && sfx[t] >= need && (t == 255 || sfx[t+1] < need)) {
      sh_prefix  = (prefix << 8) | (uint32_t)t;
      sh_kremain = need - ((t == 255) ? 0u : sfx[t+1]);
    }
    __syncthreads();
    prefix = sh_prefix;
  }
  const uint32_t T = prefix;            // exact bit pattern of the 256th-largest
  for (int s = t; s < n; s += 512)
    if (su[s] > T) { uint32_t p = atomicAdd(&sh_cnt, 1u); lidx[p] = s; }
  __syncthreads();
  for (int s = t; s < n; s += 512)
    if (su[s] == T) {
      uint32_t p = atomicAdd(&sh_cnt, 1u);
      if (p < HEAVY) lidx[p] = s;
    }
  __syncthreads();
  // ---- QK: 2 threads per token, 256B each, 4-way ILP, NT ----
  {
    int j = t >> 1, half = t & 1;
    int s = lidx[j];
    float p;
    if (s == pos) {
      float a0 = 0.f;
      #pragma unroll
      for (int i = 0; i < 16; ++i)
        a0 += dotv(kb4[half*16 + i], qb4[half*16 + i]);
      p = a0;
    } else {
      const float* kk = k_cache + (((size_t)b*SEQ + s)*NH + h)*HD + half*64;
      float a0=0.f, a1=0.f, a2=0.f, a3=0.f;
      #pragma unroll
      for (int i = 0; i < 16; i += 4) {
        a0 += dotv(ldnt(kk + (i+0)*4), qb4[half*16 + i+0]);
        a1 += dotv(ldnt(kk + (i+1)*4), qb4[half*16 + i+1]);
        a2 += dotv(ldnt(kk + (i+2)*4), qb4[half*16 + i+2]);
        a3 += dotv(ldnt(kk + (i+3)*4), qb4[half*16 + i+3]);
      }
      p = (a0+a1)+(a2+a3);
    }
    p += __shfl_xor(p, 1, 64);
    if (half == 0) sc[j] = p * 0.088388347648318447f;   // 1/sqrt(128)
  }
  __syncthreads();
  // ---- softmax over 256 scores (threads 0..255 = waves 0..3) ----
  float v = 0.f, p = 0.f, sum = 0.f;
  if (t < 256) {
    v = sc[t];
    float m = v;
    #pragma unroll
    for (int off = 32; off; off >>= 1) m = fmaxf(m, __shfl_xor(m, off, 64));
    if ((t & 63) == 0) red8[t >> 6] = m;
  }
  __syncthreads();
  if (t == 0) s_m = fmaxf(fmaxf(red8[0], red8[1]), fmaxf(red8[2], red8[3]));
  __syncthreads();
  if (t < 256) {
    p = expf(v - s_m);
    sum = p;
    #pragma unroll
    for (int off = 32; off; off >>= 1) sum += __shfl_xor(sum, off, 64);
    if ((t & 63) == 0) red8[4 + (t >> 6)] = sum;
  }
  __syncthreads();
  if (t == 0) s_sum = (red8[4] + red8[5]) + (red8[6] + red8[7]);
  __syncthreads();
  if (t < 256) sc[t] = p / s_sum;
  __syncthreads();
  // ---- PV: 16 token-streams x 32 f4-dims, NT ----
  {
    int d4 = t & 31, strm = t >> 5;
    const float* vnew = qkv + (size_t)b*3*DIM + 2*DIM + h*HD;
    f4 acc = {0.f, 0.f, 0.f, 0.f};
    for (int j = strm; j < HEAVY; j += 16) {
      int s = lidx[j];
      if (s == pos) acc += sc[j] * ld4(vnew + d4*4);
      else          acc += sc[j] * ldnt(v_cache + (((size_t)b*SEQ + s)*NH + h)*HD + d4*4);
    }
    ovv[strm][d4] = acc;
  }
  __syncthreads();
  if (t < 32) {
    f4 s = {0.f, 0.f, 0.f, 0.f};
    #pragma unroll
    for (int j = 0; j < 16; ++j) s += ovv[j][t];
    *(f4*)(o + (size_t)bh*HD + t*4) = s;
  }
}

extern "C" void kernel_launch(void* const* d_in, const int* in_sizes, int n_in,
                              void* d_out, int out_size, void* d_ws, size_t ws_size,
                              hipStream_t stream) {
  const float* x              = (const float*)d_in[0];
  const float* wqkv           = (const float*)d_in[1];
  const float* wo             = (const float*)d_in[2];
  const float* w1             = (const float*)d_in[3];
  const float* w2             = (const float*)d_in[4];
  const float* w3             = (const float*)d_in[5];
  const float* attn_norm_w    = (const float*)d_in[6];
  const float* ffn_norm_w     = (const float*)d_in[7];
  const float* k_cache        = (const float*)d_in[8];
  const float* v_cache        = (const float*)d_in[9];
  const float* k_label_cache  = (const float*)d_in[10];
  const float* freqs          = (const float*)d_in[11];
  // d_in[12] = mask1 (0 for s<=pos, -1e9 else) — realized via the s<n range
  const int*   sorted_channel = (const int*)d_in[13];
  const int*   pos_p          = (const int*)d_in[14];
  // d_in[15] = heavy_const (256, hardcoded)

  float* ws    = (float*)d_ws;
  float* qkv   = ws;                          // 4*12288 (raw q,k; v used directly)
  float* q_rot = qkv + NB*3*DIM;              // 128*128
  float* k_rot = q_rot + NB*NH*HD;            // 128*128
  float* o     = k_rot + NB*NH*HD;            // 4*4096
  float* h     = o + NB*DIM;                  // 4*4096
  float* g     = h + NB*DIM;                  // 4*11008
  uint32_t* su = (uint32_t*)(g + NB*INTER);   // 128*4096

  qkv_norm_k<2>  <<<3*DIM/2, 256, 0, stream>>>(wqkv, x, attn_norm_w, qkv);
  scores_rope_k  <<<NB*NH*4, 256, 0, stream>>>(qkv, freqs, sorted_channel,
                                               k_label_cache, pos_p, su, q_rot, k_rot);
  selattn_k      <<<NB*NH,   512, 0, stream>>>(su, q_rot, k_rot, qkv,
                                               k_cache, v_cache, pos_p, o);
  wo_k<2>        <<<DIM/2,   256, 0, stream>>>(wo, o, x, h);
  ffn13_norm_k<2><<<INTER/2, 256, 0, stream>>>(w1, w3, h, ffn_norm_w, g);
  w2_k<2>        <<<DIM/2,   256, 0, stream>>>(w2, g, h, (float*)d_out);
}

// Round 9
// 212.313 us; speedup vs baseline: 1.1274x; 1.1274x over previous
//
#include <hip/hip_runtime.h>
#include <math.h>

#define NB 4
#define SEQ 4096
#define NH 32
#define HD 128
#define DIM 4096
#define INTER 11008
#define HC 32
#define HEAVY 256
#define EPS 1e-5f

typedef float f4 __attribute__((ext_vector_type(4)));

__device__ __forceinline__ float dotv(f4 a, f4 b) {
  f4 p = a * b;
  return p.x + p.y + p.z + p.w;
}
__device__ __forceinline__ f4 ld4(const float* p) { return *(const f4*)p; }
__device__ __forceinline__ f4 ldnt(const float* p) {
  return __builtin_nontemporal_load((const f4*)p);
}

__device__ __forceinline__ float wave_sum(float v) {
  #pragma unroll
  for (int off = 32; off; off >>= 1) v += __shfl_down(v, off, 64);
  return v;
}

// ---------- persistent QKV GEMV with fused RMSNorm (rs deferred) ----------
// x/nw loaded once per block; block grid-strides over R-row chunks.
template<int R>
__global__ __launch_bounds__(256) void qkv_norm_k(const float* __restrict__ w,
                                                  const float* __restrict__ x,
                                                  const float* __restrict__ nw,
                                                  float* __restrict__ out,
                                                  int nch) {
  const int t = threadIdx.x;
  const int lane = t & 63, wi = t >> 6;
  __shared__ float redn[4][NB];
  __shared__ float red[2][4][R*NB];
  f4 xr[NB][4];
  #pragma unroll
  for (int b = 0; b < NB; ++b)
    #pragma unroll
    for (int j = 0; j < 4; ++j)
      xr[b][j] = ld4(x + b*DIM + (j*256 + t)*4);
  #pragma unroll
  for (int b = 0; b < NB; ++b) {
    float ss = 0.f;
    #pragma unroll
    for (int j = 0; j < 4; ++j) ss += dotv(xr[b][j], xr[b][j]);
    ss = wave_sum(ss);
    if (lane == 0) redn[wi][b] = ss;
  }
  #pragma unroll
  for (int j = 0; j < 4; ++j) {
    f4 aw = ld4(nw + (j*256 + t)*4);
    #pragma unroll
    for (int b = 0; b < NB; ++b) xr[b][j] *= aw;
  }
  int parity = 0;
  for (int ch = blockIdx.x; ch < nch; ch += gridDim.x, parity ^= 1) {
    const int r0 = ch * R;
    float acc[R][NB];
    #pragma unroll
    for (int r = 0; r < R; ++r)
      #pragma unroll
      for (int b = 0; b < NB; ++b) acc[r][b] = 0.f;
    #pragma unroll
    for (int r = 0; r < R; ++r) {
      const float* wr = w + (size_t)(r0 + r) * DIM;
      #pragma unroll
      for (int j = 0; j < 4; ++j) {
        f4 wv = ld4(wr + (j*256 + t)*4);
        #pragma unroll
        for (int b = 0; b < NB; ++b) acc[r][b] += dotv(wv, xr[b][j]);
      }
    }
    #pragma unroll
    for (int r = 0; r < R; ++r)
      #pragma unroll
      for (int b = 0; b < NB; ++b) {
        float v = wave_sum(acc[r][b]);
        if (lane == 0) red[parity][wi][r*NB + b] = v;
      }
    __syncthreads();                    // one barrier per chunk (red parity-dbuf)
    if (t < R*NB) {
      int r = t >> 2, b = t & 3;
      float rs = rsqrtf((redn[0][b]+redn[1][b]+redn[2][b]+redn[3][b]) * (1.f/DIM) + EPS);
      float s = red[parity][0][t] + red[parity][1][t] + red[parity][2][t] + red[parity][3][t];
      out[(size_t)b*(3*DIM) + r0 + r] = rs * s;
    }
  }
}

// ---------- persistent Wo GEMV + residual (NT weights) ----------
template<int R>
__global__ __launch_bounds__(256) void wo_k(const float* __restrict__ w,
                                            const float* __restrict__ x,
                                            const float* __restrict__ resid,
                                            float* __restrict__ out,
                                            int nch) {
  const int t = threadIdx.x;
  const int lane = t & 63, wi = t >> 6;
  __shared__ float red[2][4][R*NB];
  f4 xr[NB][4];
  #pragma unroll
  for (int b = 0; b < NB; ++b)
    #pragma unroll
    for (int j = 0; j < 4; ++j)
      xr[b][j] = ld4(x + b*DIM + (j*256 + t)*4);
  int parity = 0;
  for (int ch = blockIdx.x; ch < nch; ch += gridDim.x, parity ^= 1) {
    const int r0 = ch * R;
    float acc[R][NB];
    #pragma unroll
    for (int r = 0; r < R; ++r)
      #pragma unroll
      for (int b = 0; b < NB; ++b) acc[r][b] = 0.f;
    #pragma unroll
    for (int r = 0; r < R; ++r) {
      const float* wr = w + (size_t)(r0 + r) * DIM;
      #pragma unroll
      for (int j = 0; j < 4; ++j) {
        f4 wv = ldnt(wr + (j*256 + t)*4);
        #pragma unroll
        for (int b = 0; b < NB; ++b) acc[r][b] += dotv(wv, xr[b][j]);
      }
    }
    #pragma unroll
    for (int r = 0; r < R; ++r)
      #pragma unroll
      for (int b = 0; b < NB; ++b) {
        float v = wave_sum(acc[r][b]);
        if (lane == 0) red[parity][wi][r*NB + b] = v;
      }
    __syncthreads();
    if (t < R*NB) {
      int r = t >> 2, b = t & 3;
      float s = red[parity][0][t] + red[parity][1][t] + red[parity][2][t] + red[parity][3][t];
      out[(size_t)b*DIM + r0 + r] = resid[(size_t)b*DIM + r0 + r] + s;
    }
  }
}

// ---------- persistent W1/W3 GEMV + SwiGLU, fused RMSNorm (rs deferred, NT) ----------
template<int R>
__global__ __launch_bounds__(256) void ffn13_norm_k(const float* __restrict__ w1,
                                                    const float* __restrict__ w3,
                                                    const float* __restrict__ h,
                                                    const float* __restrict__ nw,
                                                    float* __restrict__ g,
                                                    int nch) {
  const int t = threadIdx.x;
  const int lane = t & 63, wi = t >> 6;
  __shared__ float redn[4][NB];
  __shared__ float red[2][4][2*R*NB];
  f4 xr[NB][4];
  #pragma unroll
  for (int b = 0; b < NB; ++b)
    #pragma unroll
    for (int j = 0; j < 4; ++j)
      xr[b][j] = ld4(h + b*DIM + (j*256 + t)*4);
  #pragma unroll
  for (int b = 0; b < NB; ++b) {
    float ss = 0.f;
    #pragma unroll
    for (int j = 0; j < 4; ++j) ss += dotv(xr[b][j], xr[b][j]);
    ss = wave_sum(ss);
    if (lane == 0) redn[wi][b] = ss;
  }
  #pragma unroll
  for (int j = 0; j < 4; ++j) {
    f4 aw = ld4(nw + (j*256 + t)*4);
    #pragma unroll
    for (int b = 0; b < NB; ++b) xr[b][j] *= aw;
  }
  int parity = 0;
  for (int ch = blockIdx.x; ch < nch; ch += gridDim.x, parity ^= 1) {
    const int r0 = ch * R;
    float a1[R][NB], a3[R][NB];
    #pragma unroll
    for (int r = 0; r < R; ++r)
      #pragma unroll
      for (int b = 0; b < NB; ++b) { a1[r][b] = 0.f; a3[r][b] = 0.f; }
    #pragma unroll
    for (int r = 0; r < R; ++r) {
      const float* wr1 = w1 + (size_t)(r0 + r) * DIM;
      const float* wr3 = w3 + (size_t)(r0 + r) * DIM;
      #pragma unroll
      for (int j = 0; j < 4; ++j) {
        f4 v1 = ldnt(wr1 + (j*256 + t)*4);
        f4 v3 = ldnt(wr3 + (j*256 + t)*4);
        #pragma unroll
        for (int b = 0; b < NB; ++b) {
          a1[r][b] += dotv(v1, xr[b][j]);
          a3[r][b] += dotv(v3, xr[b][j]);
        }
      }
    }
    #pragma unroll
    for (int r = 0; r < R; ++r)
      #pragma unroll
      for (int b = 0; b < NB; ++b) {
        float v = wave_sum(a1[r][b]);
        if (lane == 0) red[parity][wi][r*NB + b] = v;
        v = wave_sum(a3[r][b]);
        if (lane == 0) red[parity][wi][R*NB + r*NB + b] = v;
      }
    __syncthreads();
    if (t < R*NB) {
      int r = t >> 2, b = t & 3;
      float rs = rsqrtf((redn[0][b]+redn[1][b]+redn[2][b]+redn[3][b]) * (1.f/DIM) + EPS);
      float d1 = rs * (red[parity][0][t] + red[parity][1][t] + red[parity][2][t] + red[parity][3][t]);
      int t3 = R*NB + t;
      float d3 = rs * (red[parity][0][t3] + red[parity][1][t3] + red[parity][2][t3] + red[parity][3][t3]);
      float s = d1 / (1.f + expf(-d1));
      g[(size_t)b*INTER + r0 + r] = s * d3;
    }
  }
}

// ---------- W2 GEMV (K=11008): barrier-free, x from L2 per f4-column (NT) ----------
template<int R>
__global__ __launch_bounds__(256) void w2_k(const float* __restrict__ w2,
                                            const float* __restrict__ g,
                                            const float* __restrict__ h,
                                            float* __restrict__ out) {
  const int t = threadIdx.x;
  const int r0 = blockIdx.x * R;
  float acc[R][NB];
  #pragma unroll
  for (int r = 0; r < R; ++r)
    #pragma unroll
    for (int b = 0; b < NB; ++b) acc[r][b] = 0.f;
  // INTER/4 = 2752 f4-columns; thread t owns columns {t + 256*i}, i = 0..10
  #pragma unroll
  for (int i = 0; i < 11; ++i) {
    const int idx = t + i*256;
    if (idx < INTER/4) {
      f4 xv[NB];
      #pragma unroll
      for (int b = 0; b < NB; ++b) xv[b] = ld4(g + (size_t)b*INTER + idx*4);
      #pragma unroll
      for (int r = 0; r < R; ++r) {
        f4 wv = ldnt(w2 + (size_t)(r0 + r)*INTER + idx*4);
        #pragma unroll
        for (int b = 0; b < NB; ++b) acc[r][b] += dotv(wv, xv[b]);
      }
    }
  }
  __shared__ float red[4][R*NB];
  const int lane = t & 63, wi = t >> 6;
  #pragma unroll
  for (int r = 0; r < R; ++r)
    #pragma unroll
    for (int b = 0; b < NB; ++b) {
      float v = wave_sum(acc[r][b]);
      if (lane == 0) red[wi][r*NB + b] = v;
    }
  __syncthreads();
  if (t < R*NB) {
    int r = t >> 2, b = t & 3;
    float s = red[0][t] + red[1][t] + red[2][t] + red[3][t];
    out[(size_t)b*DIM + r0 + r] = h[(size_t)b*DIM + r0 + r] + s;
  }
}

// ---------- fused RoPE + label scores: 4 s-chunks per (b,h), full GPU ----------
__global__ __launch_bounds__(256) void scores_rope_k(const float* __restrict__ qkv,
                                                     const float* __restrict__ freqs,
                                                     const int* __restrict__ chan,
                                                     const float* __restrict__ klab_cache,
                                                     const int* __restrict__ pos_p,
                                                     uint32_t* __restrict__ su,
                                                     float* __restrict__ q_rot,
                                                     float* __restrict__ k_rot) {
  int bc = blockIdx.x; int c = bc & 3; int bh = bc >> 2;
  int b = bh >> 5, h = bh & 31;
  int pos = *pos_p; int n = pos + 1;
  int t = threadIdx.x;
  __shared__ float qs[HD], ks[HD], qv[HC], kls[HC];
  const float* qp = qkv + (size_t)b*3*DIM + h*HD;
  const float* kp = qp + DIM;
  if (t < 64) {
    float cc = freqs[2*t], sn = freqs[2*t+1];
    float q0 = qp[2*t], q1 = qp[2*t+1];
    float k0 = kp[2*t], k1 = kp[2*t+1];
    qs[2*t] = q0*cc - q1*sn; qs[2*t+1] = q1*cc + q0*sn;
    ks[2*t] = k0*cc - k1*sn; ks[2*t+1] = k1*cc + k0*sn;
  }
  __syncthreads();
  if (t < HC) { int ch = chan[h*HC + t]; qv[t] = qs[ch]; kls[t] = ks[ch]; }
  if (c == 0 && t < HD) {
    q_rot[(size_t)bh*HD + t] = qs[t];
    k_rot[(size_t)bh*HD + t] = ks[t];
  }
  __syncthreads();
  int chunk = (n + 3) >> 2;
  int s0 = c * chunk, s1 = min(n, s0 + chunk);
  for (int s = s0 + t; s < s1; s += 256) {
    float acc = 0.f;
    if (s == pos) {
      #pragma unroll
      for (int j = 0; j < HC; ++j) acc += qv[j] * kls[j];
    } else {
      const float* kl = klab_cache + (((size_t)b*SEQ + s)*NH + h)*HC;
      #pragma unroll
      for (int c4 = 0; c4 < HC/4; ++c4) {
        f4 kv = ld4(kl + c4*4);
        acc += qv[c4*4+0]*kv.x + qv[c4*4+1]*kv.y + qv[c4*4+2]*kv.z + qv[c4*4+3]*kv.w;
      }
    }
    uint32_t u = __float_as_uint(acc);
    u = (u & 0x80000000u) ? ~u : (u | 0x80000000u);   // monotone map, desc order
    su[(size_t)bh*SEQ + s] = u;
  }
}

// ---------- radix top-256 + gather attention, one (b,h) per block ----------
__global__ __launch_bounds__(512) void selattn_k(const uint32_t* __restrict__ su_g,
                                                 const float* __restrict__ q_rot,
                                                 const float* __restrict__ k_rot,
                                                 const float* __restrict__ qkv,
                                                 const float* __restrict__ k_cache,
                                                 const float* __restrict__ v_cache,
                                                 const int* __restrict__ pos_p,
                                                 float* __restrict__ o) {
  const int bh = blockIdx.x, b = bh >> 5, h = bh & 31;
  const int pos = *pos_p, n = pos + 1;
  const int t = threadIdx.x;
  __shared__ uint32_t su[SEQ];          // 16 KB
  __shared__ uint32_t hist[256], sfx[256];
  __shared__ uint32_t sh_prefix, sh_kremain, sh_cnt;
  __shared__ int lidx[HEAVY];
  __shared__ float sc[HEAVY], red8[8];
  __shared__ f4 qb4[HD/4], kb4[HD/4];
  __shared__ f4 ovv[16][32];            // 8 KB
  __shared__ float s_m, s_sum;
  if (t == 0) { sh_prefix = 0; sh_kremain = HEAVY; sh_cnt = 0; }
  if (t < 32) { qb4[t] = ld4(q_rot + (size_t)bh*HD + t*4);
                kb4[t] = ld4(k_rot + (size_t)bh*HD + t*4); }
  for (int s = t; s < n; s += 512) su[s] = su_g[(size_t)bh*SEQ + s];
  __syncthreads();
  // ---- radix-select the 256th-largest (4 passes, parallel suffix scan) ----
  uint32_t prefix = 0;
  for (int pass = 0; pass < 4; ++pass) {
    int shift = 24 - 8*pass;
    if (t < 256) hist[t] = 0;
    __syncthreads();
    for (int s = t; s < n; s += 512) {
      uint32_t u = su[s];
      bool m = (pass == 0) || ((u >> (shift + 8)) == prefix);
      if (m) atomicAdd(&hist[(u >> shift) & 255u], 1u);
    }
    __syncthreads();
    uint32_t need = sh_kremain;
    if (t < 256) sfx[t] = hist[t];
    __syncthreads();
    #pragma unroll
    for (int off = 1; off < 256; off <<= 1) {
      uint32_t v = 0, a = 0;
      if (t < 256) { v = sfx[t]; a = (t + off < 256) ? sfx[t + off] : 0u; }
      __syncthreads();
      if (t < 256) sfx[t] = v + a;
      __syncthreads();
    }
    if (t < 256 && sfx[t] >= need && (t == 255 || sfx[t+1] < need)) {
      sh_prefix  = (prefix << 8) | (uint32_t)t;
      sh_kremain = need - ((t == 255) ? 0u : sfx[t+1]);
    }
    __syncthreads();
    prefix = sh_prefix;
  }
  const uint32_t T = prefix;            // exact bit pattern of the 256th-largest
  for (int s = t; s < n; s += 512)
    if (su[s] > T) { uint32_t p = atomicAdd(&sh_cnt, 1u); lidx[p] = s; }
  __syncthreads();
  for (int s = t; s < n; s += 512)
    if (su[s] == T) {
      uint32_t p = atomicAdd(&sh_cnt, 1u);
      if (p < HEAVY) lidx[p] = s;
    }
  __syncthreads();
  // ---- QK: 2 threads per token, 256B each, 4-way ILP (cacheable) ----
  {
    int j = t >> 1, half = t & 1;
    int s = lidx[j];
    float p;
    if (s == pos) {
      float a0 = 0.f;
      #pragma unroll
      for (int i = 0; i < 16; ++i)
        a0 += dotv(kb4[half*16 + i], qb4[half*16 + i]);
      p = a0;
    } else {
      const float* kk = k_cache + (((size_t)b*SEQ + s)*NH + h)*HD + half*64;
      float a0=0.f, a1=0.f, a2=0.f, a3=0.f;
      #pragma unroll
      for (int i = 0; i < 16; i += 4) {
        a0 += dotv(ld4(kk + (i+0)*4), qb4[half*16 + i+0]);
        a1 += dotv(ld4(kk + (i+1)*4), qb4[half*16 + i+1]);
        a2 += dotv(ld4(kk + (i+2)*4), qb4[half*16 + i+2]);
        a3 += dotv(ld4(kk + (i+3)*4), qb4[half*16 + i+3]);
      }
      p = (a0+a1)+(a2+a3);
    }
    p += __shfl_xor(p, 1, 64);
    if (half == 0) sc[j] = p * 0.088388347648318447f;   // 1/sqrt(128)
  }
  __syncthreads();
  // ---- softmax over 256 scores (threads 0..255 = waves 0..3) ----
  float v = 0.f, p = 0.f, sum = 0.f;
  if (t < 256) {
    v = sc[t];
    float m = v;
    #pragma unroll
    for (int off = 32; off; off >>= 1) m = fmaxf(m, __shfl_xor(m, off, 64));
    if ((t & 63) == 0) red8[t >> 6] = m;
  }
  __syncthreads();
  if (t == 0) s_m = fmaxf(fmaxf(red8[0], red8[1]), fmaxf(red8[2], red8[3]));
  __syncthreads();
  if (t < 256) {
    p = expf(v - s_m);
    sum = p;
    #pragma unroll
    for (int off = 32; off; off >>= 1) sum += __shfl_xor(sum, off, 64);
    if ((t & 63) == 0) red8[4 + (t >> 6)] = sum;
  }
  __syncthreads();
  if (t == 0) s_sum = (red8[4] + red8[5]) + (red8[6] + red8[7]);
  __syncthreads();
  if (t < 256) sc[t] = p / s_sum;
  __syncthreads();
  // ---- PV: 16 token-streams x 32 f4-dims (cacheable) ----
  {
    int d4 = t & 31, strm = t >> 5;
    const float* vnew = qkv + (size_t)b*3*DIM + 2*DIM + h*HD;
    f4 acc = {0.f, 0.f, 0.f, 0.f};
    for (int j = strm; j < HEAVY; j += 16) {
      int s = lidx[j];
      const float* vp = (s == pos) ? vnew
                                   : (v_cache + (((size_t)b*SEQ + s)*NH + h)*HD);
      acc += sc[j] * ld4(vp + d4*4);
    }
    ovv[strm][d4] = acc;
  }
  __syncthreads();
  if (t < 32) {
    f4 s = {0.f, 0.f, 0.f, 0.f};
    #pragma unroll
    for (int j = 0; j < 16; ++j) s += ovv[j][t];
    *(f4*)(o + (size_t)bh*HD + t*4) = s;
  }
}

extern "C" void kernel_launch(void* const* d_in, const int* in_sizes, int n_in,
                              void* d_out, int out_size, void* d_ws, size_t ws_size,
                              hipStream_t stream) {
  const float* x              = (const float*)d_in[0];
  const float* wqkv           = (const float*)d_in[1];
  const float* wo             = (const float*)d_in[2];
  const float* w1             = (const float*)d_in[3];
  const float* w2             = (const float*)d_in[4];
  const float* w3             = (const float*)d_in[5];
  const float* attn_norm_w    = (const float*)d_in[6];
  const float* ffn_norm_w     = (const float*)d_in[7];
  const float* k_cache        = (const float*)d_in[8];
  const float* v_cache        = (const float*)d_in[9];
  const float* k_label_cache  = (const float*)d_in[10];
  const float* freqs          = (const float*)d_in[11];
  // d_in[12] = mask1 (0 for s<=pos, -1e9 else) — realized via the s<n range
  const int*   sorted_channel = (const int*)d_in[13];
  const int*   pos_p          = (const int*)d_in[14];
  // d_in[15] = heavy_const (256, hardcoded)

  float* ws    = (float*)d_ws;
  float* qkv   = ws;                          // 4*12288 (raw q,k; v used directly)
  float* q_rot = qkv + NB*3*DIM;              // 128*128
  float* k_rot = q_rot + NB*NH*HD;            // 128*128
  float* o     = k_rot + NB*NH*HD;            // 4*4096
  float* h     = o + NB*DIM;                  // 4*4096
  float* g     = h + NB*DIM;                  // 4*11008
  uint32_t* su = (uint32_t*)(g + NB*INTER);   // 128*4096

  qkv_norm_k<2>  <<<2048,    256, 0, stream>>>(wqkv, x, attn_norm_w, qkv, 3*DIM/2);
  scores_rope_k  <<<NB*NH*4, 256, 0, stream>>>(qkv, freqs, sorted_channel,
                                               k_label_cache, pos_p, su, q_rot, k_rot);
  selattn_k      <<<NB*NH,   512, 0, stream>>>(su, q_rot, k_rot, qkv,
                                               k_cache, v_cache, pos_p, o);
  wo_k<2>        <<<1024,    256, 0, stream>>>(wo, o, x, h, DIM/2);
  ffn13_norm_k<2><<<2048,    256, 0, stream>>>(w1, w3, h, ffn_norm_w, g, INTER/2);
  w2_k<2>        <<<DIM/2,   256, 0, stream>>>(w2, g, h, (float*)d_out);
}

// Round 10
// 209.677 us; speedup vs baseline: 1.1416x; 1.0126x over previous
//
#include <hip/hip_runtime.h>
#include <math.h>

#define NB 4
#define SEQ 4096
#define NH 32
#define HD 128
#define DIM 4096
#define INTER 11008
#define HC 32
#define HEAVY 256
#define EPS 1e-5f

typedef float f4 __attribute__((ext_vector_type(4)));

__device__ __forceinline__ float dotv(f4 a, f4 b) {
  f4 p = a * b;
  return p.x + p.y + p.z + p.w;
}
__device__ __forceinline__ f4 ld4(const float* p) { return *(const f4*)p; }
__device__ __forceinline__ f4 ldnt(const float* p) {
  return __builtin_nontemporal_load((const f4*)p);
}

__device__ __forceinline__ float wave_sum(float v) {
  #pragma unroll
  for (int off = 32; off; off >>= 1) v += __shfl_down(v, off, 64);
  return v;
}

// ---------- persistent QKV GEMV with fused RMSNorm (rs deferred) ----------
template<int R>
__global__ __launch_bounds__(256) void qkv_norm_k(const float* __restrict__ w,
                                                  const float* __restrict__ x,
                                                  const float* __restrict__ nw,
                                                  float* __restrict__ out,
                                                  int nch) {
  const int t = threadIdx.x;
  const int lane = t & 63, wi = t >> 6;
  __shared__ float redn[4][NB];
  __shared__ float red[2][4][R*NB];
  f4 xr[NB][4];
  #pragma unroll
  for (int b = 0; b < NB; ++b)
    #pragma unroll
    for (int j = 0; j < 4; ++j)
      xr[b][j] = ld4(x + b*DIM + (j*256 + t)*4);
  #pragma unroll
  for (int b = 0; b < NB; ++b) {
    float ss = 0.f;
    #pragma unroll
    for (int j = 0; j < 4; ++j) ss += dotv(xr[b][j], xr[b][j]);
    ss = wave_sum(ss);
    if (lane == 0) redn[wi][b] = ss;
  }
  #pragma unroll
  for (int j = 0; j < 4; ++j) {
    f4 aw = ld4(nw + (j*256 + t)*4);
    #pragma unroll
    for (int b = 0; b < NB; ++b) xr[b][j] *= aw;
  }
  int parity = 0;
  for (int ch = blockIdx.x; ch < nch; ch += gridDim.x, parity ^= 1) {
    const int r0 = ch * R;
    float acc[R][NB];
    #pragma unroll
    for (int r = 0; r < R; ++r)
      #pragma unroll
      for (int b = 0; b < NB; ++b) acc[r][b] = 0.f;
    #pragma unroll
    for (int r = 0; r < R; ++r) {
      const float* wr = w + (size_t)(r0 + r) * DIM;
      #pragma unroll
      for (int j = 0; j < 4; ++j) {
        f4 wv = ld4(wr + (j*256 + t)*4);
        #pragma unroll
        for (int b = 0; b < NB; ++b) acc[r][b] += dotv(wv, xr[b][j]);
      }
    }
    #pragma unroll
    for (int r = 0; r < R; ++r)
      #pragma unroll
      for (int b = 0; b < NB; ++b) {
        float v = wave_sum(acc[r][b]);
        if (lane == 0) red[parity][wi][r*NB + b] = v;
      }
    __syncthreads();
    if (t < R*NB) {
      int r = t >> 2, b = t & 3;
      float rs = rsqrtf((redn[0][b]+redn[1][b]+redn[2][b]+redn[3][b]) * (1.f/DIM) + EPS);
      float s = red[parity][0][t] + red[parity][1][t] + red[parity][2][t] + red[parity][3][t];
      out[(size_t)b*(3*DIM) + r0 + r] = rs * s;
    }
  }
}

// ---------- persistent Wo GEMV + residual (NT weights) ----------
template<int R>
__global__ __launch_bounds__(256) void wo_k(const float* __restrict__ w,
                                            const float* __restrict__ x,
                                            const float* __restrict__ resid,
                                            float* __restrict__ out,
                                            int nch) {
  const int t = threadIdx.x;
  const int lane = t & 63, wi = t >> 6;
  __shared__ float red[2][4][R*NB];
  f4 xr[NB][4];
  #pragma unroll
  for (int b = 0; b < NB; ++b)
    #pragma unroll
    for (int j = 0; j < 4; ++j)
      xr[b][j] = ld4(x + b*DIM + (j*256 + t)*4);
  int parity = 0;
  for (int ch = blockIdx.x; ch < nch; ch += gridDim.x, parity ^= 1) {
    const int r0 = ch * R;
    float acc[R][NB];
    #pragma unroll
    for (int r = 0; r < R; ++r)
      #pragma unroll
      for (int b = 0; b < NB; ++b) acc[r][b] = 0.f;
    #pragma unroll
    for (int r = 0; r < R; ++r) {
      const float* wr = w + (size_t)(r0 + r) * DIM;
      #pragma unroll
      for (int j = 0; j < 4; ++j) {
        f4 wv = ldnt(wr + (j*256 + t)*4);
        #pragma unroll
        for (int b = 0; b < NB; ++b) acc[r][b] += dotv(wv, xr[b][j]);
      }
    }
    #pragma unroll
    for (int r = 0; r < R; ++r)
      #pragma unroll
      for (int b = 0; b < NB; ++b) {
        float v = wave_sum(acc[r][b]);
        if (lane == 0) red[parity][wi][r*NB + b] = v;
      }
    __syncthreads();
    if (t < R*NB) {
      int r = t >> 2, b = t & 3;
      float s = red[parity][0][t] + red[parity][1][t] + red[parity][2][t] + red[parity][3][t];
      out[(size_t)b*DIM + r0 + r] = resid[(size_t)b*DIM + r0 + r] + s;
    }
  }
}

// ---------- persistent W1/W3 GEMV + SwiGLU, fused RMSNorm (rs deferred, NT) ----------
template<int R>
__global__ __launch_bounds__(256) void ffn13_norm_k(const float* __restrict__ w1,
                                                    const float* __restrict__ w3,
                                                    const float* __restrict__ h,
                                                    const float* __restrict__ nw,
                                                    float* __restrict__ g,
                                                    int nch) {
  const int t = threadIdx.x;
  const int lane = t & 63, wi = t >> 6;
  __shared__ float redn[4][NB];
  __shared__ float red[2][4][2*R*NB];
  f4 xr[NB][4];
  #pragma unroll
  for (int b = 0; b < NB; ++b)
    #pragma unroll
    for (int j = 0; j < 4; ++j)
      xr[b][j] = ld4(h + b*DIM + (j*256 + t)*4);
  #pragma unroll
  for (int b = 0; b < NB; ++b) {
    float ss = 0.f;
    #pragma unroll
    for (int j = 0; j < 4; ++j) ss += dotv(xr[b][j], xr[b][j]);
    ss = wave_sum(ss);
    if (lane == 0) redn[wi][b] = ss;
  }
  #pragma unroll
  for (int j = 0; j < 4; ++j) {
    f4 aw = ld4(nw + (j*256 + t)*4);
    #pragma unroll
    for (int b = 0; b < NB; ++b) xr[b][j] *= aw;
  }
  int parity = 0;
  for (int ch = blockIdx.x; ch < nch; ch += gridDim.x, parity ^= 1) {
    const int r0 = ch * R;
    float a1[R][NB], a3[R][NB];
    #pragma unroll
    for (int r = 0; r < R; ++r)
      #pragma unroll
      for (int b = 0; b < NB; ++b) { a1[r][b] = 0.f; a3[r][b] = 0.f; }
    #pragma unroll
    for (int r = 0; r < R; ++r) {
      const float* wr1 = w1 + (size_t)(r0 + r) * DIM;
      const float* wr3 = w3 + (size_t)(r0 + r) * DIM;
      #pragma unroll
      for (int j = 0; j < 4; ++j) {
        f4 v1 = ldnt(wr1 + (j*256 + t)*4);
        f4 v3 = ldnt(wr3 + (j*256 + t)*4);
        #pragma unroll
        for (int b = 0; b < NB; ++b) {
          a1[r][b] += dotv(v1, xr[b][j]);
          a3[r][b] += dotv(v3, xr[b][j]);
        }
      }
    }
    #pragma unroll
    for (int r = 0; r < R; ++r)
      #pragma unroll
      for (int b = 0; b < NB; ++b) {
        float v = wave_sum(a1[r][b]);
        if (lane == 0) red[parity][wi][r*NB + b] = v;
        v = wave_sum(a3[r][b]);
        if (lane == 0) red[parity][wi][R*NB + r*NB + b] = v;
      }
    __syncthreads();
    if (t < R*NB) {
      int r = t >> 2, b = t & 3;
      float rs = rsqrtf((redn[0][b]+redn[1][b]+redn[2][b]+redn[3][b]) * (1.f/DIM) + EPS);
      float d1 = rs * (red[parity][0][t] + red[parity][1][t] + red[parity][2][t] + red[parity][3][t]);
      int t3 = R*NB + t;
      float d3 = rs * (red[parity][0][t3] + red[parity][1][t3] + red[parity][2][t3] + red[parity][3][t3]);
      float s = d1 / (1.f + expf(-d1));
      g[(size_t)b*INTER + r0 + r] = s * d3;
    }
  }
}

// ---------- W2 GEMV (K=11008): barrier-free, x from L2 per f4-column (NT) ----------
template<int R>
__global__ __launch_bounds__(256) void w2_k(const float* __restrict__ w2,
                                            const float* __restrict__ g,
                                            const float* __restrict__ h,
                                            float* __restrict__ out) {
  const int t = threadIdx.x;
  const int r0 = blockIdx.x * R;
  float acc[R][NB];
  #pragma unroll
  for (int r = 0; r < R; ++r)
    #pragma unroll
    for (int b = 0; b < NB; ++b) acc[r][b] = 0.f;
  #pragma unroll
  for (int i = 0; i < 11; ++i) {
    const int idx = t + i*256;
    if (idx < INTER/4) {
      f4 xv[NB];
      #pragma unroll
      for (int b = 0; b < NB; ++b) xv[b] = ld4(g + (size_t)b*INTER + idx*4);
      #pragma unroll
      for (int r = 0; r < R; ++r) {
        f4 wv = ldnt(w2 + (size_t)(r0 + r)*INTER + idx*4);
        #pragma unroll
        for (int b = 0; b < NB; ++b) acc[r][b] += dotv(wv, xv[b]);
      }
    }
  }
  __shared__ float red[4][R*NB];
  const int lane = t & 63, wi = t >> 6;
  #pragma unroll
  for (int r = 0; r < R; ++r)
    #pragma unroll
    for (int b = 0; b < NB; ++b) {
      float v = wave_sum(acc[r][b]);
      if (lane == 0) red[wi][r*NB + b] = v;
    }
  __syncthreads();
  if (t < R*NB) {
    int r = t >> 2, b = t & 3;
    float s = red[0][t] + red[1][t] + red[2][t] + red[3][t];
    out[(size_t)b*DIM + r0 + r] = h[(size_t)b*DIM + r0 + r] + s;
  }
}

// ---------- fused RoPE + label scores: 8 s-chunks per (b,h), 1024 blocks ----------
__global__ __launch_bounds__(256) void scores_rope_k(const float* __restrict__ qkv,
                                                     const float* __restrict__ freqs,
                                                     const int* __restrict__ chan,
                                                     const float* __restrict__ klab_cache,
                                                     const int* __restrict__ pos_p,
                                                     uint32_t* __restrict__ su,
                                                     float* __restrict__ q_rot,
                                                     float* __restrict__ k_rot) {
  int bc = blockIdx.x; int c = bc & 7; int bh = bc >> 3;
  int b = bh >> 5, h = bh & 31;
  int pos = *pos_p; int n = pos + 1;
  int t = threadIdx.x;
  __shared__ float qs[HD], ks[HD], qv[HC], kls[HC];
  const float* qp = qkv + (size_t)b*3*DIM + h*HD;
  const float* kp = qp + DIM;
  if (t < 64) {
    float cc = freqs[2*t], sn = freqs[2*t+1];
    float q0 = qp[2*t], q1 = qp[2*t+1];
    float k0 = kp[2*t], k1 = kp[2*t+1];
    qs[2*t] = q0*cc - q1*sn; qs[2*t+1] = q1*cc + q0*sn;
    ks[2*t] = k0*cc - k1*sn; ks[2*t+1] = k1*cc + k0*sn;
  }
  __syncthreads();
  if (t < HC) { int ch = chan[h*HC + t]; qv[t] = qs[ch]; kls[t] = ks[ch]; }
  if (c == 0 && t < HD) {
    q_rot[(size_t)bh*HD + t] = qs[t];
    k_rot[(size_t)bh*HD + t] = ks[t];
  }
  __syncthreads();
  int chunk = (n + 7) >> 3;
  int s0 = c * chunk, s1 = min(n, s0 + chunk);
  for (int s = s0 + t; s < s1; s += 256) {
    float acc = 0.f;
    if (s == pos) {
      #pragma unroll
      for (int j = 0; j < HC; ++j) acc += qv[j] * kls[j];
    } else {
      const float* kl = klab_cache + (((size_t)b*SEQ + s)*NH + h)*HC;
      #pragma unroll
      for (int c4 = 0; c4 < HC/4; ++c4) {
        f4 kv = ld4(kl + c4*4);
        acc += qv[c4*4+0]*kv.x + qv[c4*4+1]*kv.y + qv[c4*4+2]*kv.z + qv[c4*4+3]*kv.w;
      }
    }
    uint32_t u = __float_as_uint(acc);
    u = (u & 0x80000000u) ? ~u : (u | 0x80000000u);   // monotone map, desc order
    su[(size_t)bh*SEQ + s] = u;
  }
}

// ---------- radix top-256 (wave-shuffle scan) + gather attention ----------
__global__ __launch_bounds__(512) void selattn_k(const uint32_t* __restrict__ su_g,
                                                 const float* __restrict__ q_rot,
                                                 const float* __restrict__ k_rot,
                                                 const float* __restrict__ qkv,
                                                 const float* __restrict__ k_cache,
                                                 const float* __restrict__ v_cache,
                                                 const int* __restrict__ pos_p,
                                                 float* __restrict__ o) {
  const int bh = blockIdx.x, b = bh >> 5, h = bh & 31;
  const int pos = *pos_p, n = pos + 1;
  const int t = threadIdx.x;
  const int lane = t & 63;
  __shared__ uint32_t su[SEQ];          // 16 KB
  __shared__ uint32_t hist[256], sfx[257];
  __shared__ uint32_t wtot[4];
  __shared__ uint32_t sh_prefix, sh_kremain, sh_cnt;
  __shared__ int lidx[HEAVY];
  __shared__ float sc[HEAVY], red8[8];
  __shared__ f4 qb4[HD/4], kb4[HD/4];
  __shared__ f4 ovv[16][32];            // 8 KB
  __shared__ float s_m, s_sum;
  if (t == 0) { sh_prefix = 0; sh_kremain = HEAVY; sh_cnt = 0; }
  if (t < 32) { qb4[t] = ld4(q_rot + (size_t)bh*HD + t*4);
                kb4[t] = ld4(k_rot + (size_t)bh*HD + t*4); }
  for (int s = t; s < n; s += 512) su[s] = su_g[(size_t)bh*SEQ + s];
  if (t == 0) sfx[256] = 0;
  __syncthreads();
  // ---- radix-select the 256th-largest: 4 passes, in-wave shuffle suffix scan ----
  uint32_t prefix = 0;
  for (int pass = 0; pass < 4; ++pass) {
    int shift = 24 - 8*pass;
    if (t < 256) hist[t] = 0;
    __syncthreads();                                        // A
    for (int s = t; s < n; s += 512) {
      uint32_t u = su[s];
      bool m = (pass == 0) || ((u >> (shift + 8)) == prefix);
      if (m) atomicAdd(&hist[(u >> shift) & 255u], 1u);
    }
    __syncthreads();                                        // B
    uint32_t need = sh_kremain;
    uint32_t v = 0;
    if (t < 256) {
      v = hist[t];
      // in-wave inclusive suffix sum over the 64 bins this wave owns
      #pragma unroll
      for (int off = 1; off < 64; off <<= 1) {
        uint32_t u = __shfl_down(v, off, 64);
        if (lane + off < 64) v += u;
      }
      if (lane == 0) wtot[t >> 6] = v;  // total of this wave's 64 bins
    }
    __syncthreads();                                        // C
    if (t < 256) {
      uint32_t add = 0;
      #pragma unroll
      for (int w = 0; w < 4; ++w) if (w > (t >> 6)) add += wtot[w];
      sfx[t] = v + add;                 // count of elements with digit >= t
    }
    __syncthreads();                                        // D
    if (t < 256 && sfx[t] >= need && sfx[t+1] < need) {
      sh_prefix  = (prefix << 8) | (uint32_t)t;
      sh_kremain = need - sfx[t+1];
    }
    __syncthreads();                                        // E
    prefix = sh_prefix;
  }
  const uint32_t T = prefix;            // exact bit pattern of the 256th-largest
  for (int s = t; s < n; s += 512)
    if (su[s] > T) { uint32_t p = atomicAdd(&sh_cnt, 1u); lidx[p] = s; }
  __syncthreads();
  for (int s = t; s < n; s += 512)
    if (su[s] == T) {
      uint32_t p = atomicAdd(&sh_cnt, 1u);
      if (p < HEAVY) lidx[p] = s;
    }
  __syncthreads();
  // ---- QK: 2 threads per token, 256B each, 4-way ILP ----
  {
    int j = t >> 1, half = t & 1;
    int s = lidx[j];
    float p;
    if (s == pos) {
      float a0 = 0.f;
      #pragma unroll
      for (int i = 0; i < 16; ++i)
        a0 += dotv(kb4[half*16 + i], qb4[half*16 + i]);
      p = a0;
    } else {
      const float* kk = k_cache + (((size_t)b*SEQ + s)*NH + h)*HD + half*64;
      float a0=0.f, a1=0.f, a2=0.f, a3=0.f;
      #pragma unroll
      for (int i = 0; i < 16; i += 4) {
        a0 += dotv(ld4(kk + (i+0)*4), qb4[half*16 + i+0]);
        a1 += dotv(ld4(kk + (i+1)*4), qb4[half*16 + i+1]);
        a2 += dotv(ld4(kk + (i+2)*4), qb4[half*16 + i+2]);
        a3 += dotv(ld4(kk + (i+3)*4), qb4[half*16 + i+3]);
      }
      p = (a0+a1)+(a2+a3);
    }
    p += __shfl_xor(p, 1, 64);
    if (half == 0) sc[j] = p * 0.088388347648318447f;   // 1/sqrt(128)
  }
  __syncthreads();
  // ---- softmax over 256 scores (threads 0..255 = waves 0..3) ----
  float v = 0.f, p = 0.f, sum = 0.f;
  if (t < 256) {
    v = sc[t];
    float m = v;
    #pragma unroll
    for (int off = 32; off; off >>= 1) m = fmaxf(m, __shfl_xor(m, off, 64));
    if (lane == 0) red8[t >> 6] = m;
  }
  __syncthreads();
  if (t == 0) s_m = fmaxf(fmaxf(red8[0], red8[1]), fmaxf(red8[2], red8[3]));
  __syncthreads();
  if (t < 256) {
    p = expf(v - s_m);
    sum = p;
    #pragma unroll
    for (int off = 32; off; off >>= 1) sum += __shfl_xor(sum, off, 64);
    if (lane == 0) red8[4 + (t >> 6)] = sum;
  }
  __syncthreads();
  if (t == 0) s_sum = (red8[4] + red8[5]) + (red8[6] + red8[7]);
  __syncthreads();
  if (t < 256) sc[t] = p / s_sum;
  __syncthreads();
  // ---- PV: 16 token-streams x 32 f4-dims ----
  {
    int d4 = t & 31, strm = t >> 5;
    const float* vnew = qkv + (size_t)b*3*DIM + 2*DIM + h*HD;
    f4 acc = {0.f, 0.f, 0.f, 0.f};
    for (int j = strm; j < HEAVY; j += 16) {
      int s = lidx[j];
      const float* vp = (s == pos) ? vnew
                                   : (v_cache + (((size_t)b*SEQ + s)*NH + h)*HD);
      acc += sc[j] * ld4(vp + d4*4);
    }
    ovv[strm][d4] = acc;
  }
  __syncthreads();
  if (t < 32) {
    f4 s = {0.f, 0.f, 0.f, 0.f};
    #pragma unroll
    for (int j = 0; j < 16; ++j) s += ovv[j][t];
    *(f4*)(o + (size_t)bh*HD + t*4) = s;
  }
}

extern "C" void kernel_launch(void* const* d_in, const int* in_sizes, int n_in,
                              void* d_out, int out_size, void* d_ws, size_t ws_size,
                              hipStream_t stream) {
  const float* x              = (const float*)d_in[0];
  const float* wqkv           = (const float*)d_in[1];
  const float* wo             = (const float*)d_in[2];
  const float* w1             = (const float*)d_in[3];
  const float* w2             = (const float*)d_in[4];
  const float* w3             = (const float*)d_in[5];
  const float* attn_norm_w    = (const float*)d_in[6];
  const float* ffn_norm_w     = (const float*)d_in[7];
  const float* k_cache        = (const float*)d_in[8];
  const float* v_cache        = (const float*)d_in[9];
  const float* k_label_cache  = (const float*)d_in[10];
  const float* freqs          = (const float*)d_in[11];
  // d_in[12] = mask1 (0 for s<=pos, -1e9 else) — realized via the s<n range
  const int*   sorted_channel = (const int*)d_in[13];
  const int*   pos_p          = (const int*)d_in[14];
  // d_in[15] = heavy_const (256, hardcoded)

  float* ws    = (float*)d_ws;
  float* qkv   = ws;                          // 4*12288 (raw q,k; v used directly)
  float* q_rot = qkv + NB*3*DIM;              // 128*128
  float* k_rot = q_rot + NB*NH*HD;            // 128*128
  float* o     = k_rot + NB*NH*HD;            // 4*4096
  float* h     = o + NB*DIM;                  // 4*4096
  float* g     = h + NB*DIM;                  // 4*11008
  uint32_t* su = (uint32_t*)(g + NB*INTER);   // 128*4096

  qkv_norm_k<2>  <<<2048,    256, 0, stream>>>(wqkv, x, attn_norm_w, qkv, 3*DIM/2);
  scores_rope_k  <<<NB*NH*8, 256, 0, stream>>>(qkv, freqs, sorted_channel,
                                               k_label_cache, pos_p, su, q_rot, k_rot);
  selattn_k      <<<NB*NH,   512, 0, stream>>>(su, q_rot, k_rot, qkv,
                                               k_cache, v_cache, pos_p, o);
  wo_k<2>        <<<1024,    256, 0, stream>>>(wo, o, x, h, DIM/2);
  ffn13_norm_k<2><<<2048,    256, 0, stream>>>(w1, w3, h, ffn_norm_w, g, INTER/2);
  w2_k<2>        <<<DIM/2,   256, 0, stream>>>(w2, g, h, (float*)d_out);
}